// Round 1
// 171.066 us; speedup vs baseline: 1.0452x; 1.0452x over previous
//
#include <hip/hip_runtime.h>

#define NMEM 16384
#define MDIM 225
#define L1D 134
#define MCLS 4489     // 67*67 real positions per class
#define PPAD 4608     // 144*32 padded positions
#define NTILE2 512    // 256 tiles * 2 surfaced candidates
#define MARGIN 0.5f

typedef __attribute__((ext_vector_type(8))) _Float16 f16x8;
typedef __attribute__((ext_vector_type(16))) float f32x16;

__device__ inline unsigned short f2h(float f) {
    const _Float16 h = (_Float16)f;
    unsigned short u; __builtin_memcpy(&u, &h, 2); return u;
}
__device__ inline _Float16 us2h(unsigned short u) {
    _Float16 h; __builtin_memcpy(&h, &u, 2); return h;
}
__device__ inline float h2f(unsigned short u) { return (float)us2h(u); }

// ---------------------------------------------------------------------------
// P0: collapsed filters -> fp16. One thread per (cls, n, k); cmh[gid].
// ---------------------------------------------------------------------------
__global__ __launch_bounds__(256) void prep_cm(const float* __restrict__ mem,
                                               unsigned short* __restrict__ cmh) {
    const int gid = blockIdx.x * 256 + threadIdx.x;   // 4*16384*64 = 2^22
    const int k = gid & 63, n = (gid >> 6) & (NMEM - 1), cls = gid >> 20;
    const int u = k >> 3, v = k & 7, er = cls >> 1, ec = cls & 1;
    const int i0 = 2 * u - er, j0 = 2 * v - ec;
    const float* mrow = mem + (size_t)n * MDIM;
    float s = 0.f;
    #pragma unroll
    for (int di = 0; di < 2; ++di) {
        const int i = i0 + di;
        if ((unsigned)i >= 15u) continue;
        #pragma unroll
        for (int dj = 0; dj < 2; ++dj) {
            const int j = j0 + dj;
            if ((unsigned)j >= 15u) continue;
            s += mrow[i * 15 + j];
        }
    }
    cmh[gid] = f2h(s);
}

// ---------------------------------------------------------------------------
// P1: hn[n] = 0.5*||mem_n||^2 (f32 for rescue) + packed fp16 (-hn_hi,-hn_lo)
// for the GEMM-folded subtraction. One wave per n.
// ---------------------------------------------------------------------------
__global__ __launch_bounds__(256) void prep_hn(const float* __restrict__ mem,
                                               float* __restrict__ hn,
                                               unsigned int* __restrict__ hnb) {
    const int wave = threadIdx.x >> 6, lane = threadIdx.x & 63;
    const int n = blockIdx.x * 4 + wave;
    const float* mrow = mem + (size_t)n * MDIM;
    float s = 0.f;
    for (int t = lane; t < MDIM; t += 64) { const float v = mrow[t]; s += v * v; }
    #pragma unroll
    for (int m = 1; m < 64; m <<= 1) s += __shfl_xor(s, m);
    if (lane == 0) {
        const float h = 0.5f * s;
        hn[n] = h;
        const unsigned short nh = f2h(-h);
        const unsigned short nl = f2h(-h - h2f(nh));
        hnb[n] = (unsigned)nh | ((unsigned)nl << 16);
    }
}

// ---------------------------------------------------------------------------
// P2: X (positions) in B-fragment layout, fp16: x[(pt*4+ks)*2+g][lane32][8j].
// ---------------------------------------------------------------------------
__global__ __launch_bounds__(256) void prep_x(const float* __restrict__ img,
                                              unsigned short* __restrict__ xh) {
    const int t = blockIdx.x * 256 + threadIdx.x;   // 144*4*2*32 = 36864
    const int nl = t & 31, g = (t >> 5) & 1, ks = (t >> 6) & 3, pt = t >> 8;
    const int pos = pt * 32 + nl;
    const int u = ks * 2 + g;
    unsigned short h[8];
    if (pos < MCLS) {
        const int mr = pos / 67, mc = pos - mr * 67;
        const int r = mr - 5 + u;
        #pragma unroll
        for (int j = 0; j < 8; ++j) {
            const int c = mc - 5 + j;
            float v = 0.f;
            if ((unsigned)r < 64u && (unsigned)c < 64u) v = img[r * 64 + c];
            h[j] = f2h(v);
        }
    } else {
        #pragma unroll
        for (int j = 0; j < 8; ++j) h[j] = 0;
    }
    #pragma unroll
    for (int j = 0; j < 8; ++j) xh[(size_t)t * 8 + j] = h[j];
}

// ---------------------------------------------------------------------------
// K1: fp16 single-product MFMA scoring. Grid (256 nblk, 4 cls), 4 waves,
// __launch_bounds__(256,4). A (64 n x 64 k) register-resident; -hn folded via
// fp16 hi/lo ext K-slice. B ping-pong double-buffered in registers (2x unroll,
// no copy movs). No LDS, no barriers.
//
// nblk is XCD-write-merge swizzled: nblk = (bx&7)*32 + (bx>>3). Blocks
// bx, bx+8, ... land on the same XCD (round-robin dispatch) and own
// CONSECUTIVE nblk, so their 8B float2 stores into the same 64B line of
// pcvT merge in that XCD's L2 (8 entries/line) instead of 8 partial-line
// HBM writes. Bijective; A-rows/hn/store all keyed off the same nblk.
//
// Epilogue: pairwise TOP-2 over 64 n (6-bit id in mantissa LSBs), exposing
// v_max3_f32 (m2 = max3(m2, lo, min(m1,hi))); exact same selection as the
// sequential scan. Stored transposed pcvT[(cls*PPAD+pos)*512 + nblk*2+{0,1}]
// via an incremented pointer (no per-iter address recompute).
// A/B frag: row=lane&31, k=(lane>>5)*8+j. C/D: col=lane&31,
// row=(r&3)+8*(r>>2)+4*(lane>>5)  [HW-verified].
// ---------------------------------------------------------------------------
__global__ __launch_bounds__(256, 4) void mfma_argmin_kernel(const unsigned short* __restrict__ cmh,
                                                             const unsigned short* __restrict__ xh,
                                                             const unsigned int* __restrict__ hnb,
                                                             float* __restrict__ pcvT) {
    const int nblk = ((blockIdx.x & 7) << 5) | (blockIdx.x >> 3);   // XCD write-merge swizzle
    const int cls = blockIdx.y;
    const int t = threadIdx.x, wave = t >> 6, lane = t & 63;
    const int g = lane >> 5, nl = lane & 31;

    // One-time A fragment loads (row nl and nl+32, all 4 K-slices).
    f16x8 a0[4], a1[4];
    #pragma unroll
    for (int ks = 0; ks < 4; ++ks) {
        const size_t base = ((size_t)(cls * NMEM + nblk * 64 + nl)) * 64 + ks * 16 + g * 8;
        a0[ks] = *(const f16x8*)(cmh + base);
        a1[ks] = *(const f16x8*)(cmh + base + 32 * 64);
    }

    // hn-folding ext slice: A_ext=(-hn_hi,-hn_lo,0..), B_ext=(1,1,0..).
    const unsigned int hp0 = hnb[nblk * 64 + nl];
    const unsigned int hp1 = hnb[nblk * 64 + 32 + nl];
    f16x8 aex0 = {0,0,0,0,0,0,0,0}, aex1 = {0,0,0,0,0,0,0,0}, bex = {0,0,0,0,0,0,0,0};
    if (g == 0) {
        aex0[0] = us2h((unsigned short)(hp0 & 0xFFFFu));
        aex0[1] = us2h((unsigned short)(hp0 >> 16));
        aex1[0] = us2h((unsigned short)(hp1 & 0xFFFFu));
        aex1[1] = us2h((unsigned short)(hp1 >> 16));
        bex[0] = (_Float16)1.0f;
        bex[1] = (_Float16)1.0f;
    }

    // B pointer for this wave/g: pt = it*4+wave  =>  +8192 halves per iter.
    const unsigned short* xp = xh + ((size_t)((wave * 4) * 2 + g)) * 256 + nl * 8;

    // Store pointer: pos = (it*4+wave)*32 + nl advances 128/iter => +65536 f.
    float* stp = pcvT + ((size_t)(cls * PPAD + wave * 32 + nl)) * NTILE2 + nblk * 2;

    f16x8 b0[4], b1[4];
    #pragma unroll
    for (int ks = 0; ks < 4; ++ks) b0[ks] = *(const f16x8*)(xp + ks * 512);

    auto body = [&](const f16x8 (&b)[4]) {
        f32x16 acc0 = {0.f,0.f,0.f,0.f,0.f,0.f,0.f,0.f,0.f,0.f,0.f,0.f,0.f,0.f,0.f,0.f};
        f32x16 acc1 = {0.f,0.f,0.f,0.f,0.f,0.f,0.f,0.f,0.f,0.f,0.f,0.f,0.f,0.f,0.f,0.f};
        __builtin_amdgcn_s_setprio(1);
        #pragma unroll
        for (int ks = 0; ks < 4; ++ks) {
            acc0 = __builtin_amdgcn_mfma_f32_32x32x16_f16(a0[ks], b[ks], acc0, 0, 0, 0);
            acc1 = __builtin_amdgcn_mfma_f32_32x32x16_f16(a1[ks], b[ks], acc1, 0, 0, 0);
        }
        acc0 = __builtin_amdgcn_mfma_f32_32x32x16_f16(aex0, bex, acc0, 0, 0, 0);
        acc1 = __builtin_amdgcn_mfma_f32_32x32x16_f16(aex1, bex, acc1, 0, 0, 0);
        __builtin_amdgcn_s_setprio(0);

        // Pairwise top-2 over 64 n, 6-bit id packed in mantissa LSBs.
        // Exact: top2({m1,m2,hi,lo}) = {max(m1,hi), max3(m2, lo, min(m1,hi))}.
        float m1 = -3.0e38f, m2 = -3.0e38f;
        #pragma unroll
        for (int r = 0; r < 16; r += 2) {
            const int ida = (r & 3) + 8 * (r >> 2) + 4 * g;   // r even => r+1 has id+1
            {
                const float v = __int_as_float((__float_as_int(acc0[r]) & ~63) | ida);
                const float w = __int_as_float((__float_as_int(acc0[r + 1]) & ~63) | (ida + 1));
                const float hi = fmaxf(v, w), lo = fminf(v, w);
                const float tm = fminf(m1, hi);
                m1 = fmaxf(m1, hi);
                m2 = fmaxf(fmaxf(m2, lo), tm);
            }
            {
                const float v = __int_as_float((__float_as_int(acc1[r]) & ~63) | (ida + 32));
                const float w = __int_as_float((__float_as_int(acc1[r + 1]) & ~63) | (ida + 33));
                const float hi = fmaxf(v, w), lo = fminf(v, w);
                const float tm = fminf(m1, hi);
                m1 = fmaxf(m1, hi);
                m2 = fmaxf(fmaxf(m2, lo), tm);
            }
        }
        const float o1 = __shfl_xor(m1, 32);
        const float o2 = __shfl_xor(m2, 32);
        const float M1 = fmaxf(m1, o1);
        const float M2 = fmaxf(fminf(m1, o1), fmaxf(m2, o2));

        if (g == 0) {
            float2 st; st.x = M1; st.y = M2;
            *(float2*)stp = st;
        }
        stp += (size_t)128 * NTILE2;
    };

    for (int it = 0; it < 36; it += 2) {
        #pragma unroll
        for (int ks = 0; ks < 4; ++ks) b1[ks] = *(const f16x8*)(xp + 8192 + ks * 512);
        body(b0);
        if (it + 2 < 36) {
            #pragma unroll
            for (int ks = 0; ks < 4; ++ks) b0[ks] = *(const f16x8*)(xp + 16384 + ks * 512);
        }
        body(b1);
        xp += 16384;
    }
}

// ---------------------------------------------------------------------------
// K2: rescue, one wave per (cls, pos): coalesced read of 512 surfaced
// candidates (256 tiles x top-2), shfl-max vmax, ballot candidates within
// MARGIN, wave-cooperative exact fp32 rescore from mem. Tie rule matches
// argmin-first.
// ---------------------------------------------------------------------------
__global__ __launch_bounds__(256) void rescue_kernel(const float* __restrict__ img,
                                                     const float* __restrict__ mem,
                                                     const float* __restrict__ hn,
                                                     const float* __restrict__ pcvT,
                                                     int* __restrict__ idx2d) {
    const int wave = threadIdx.x >> 6, lane = threadIdx.x & 63;
    const int cls = blockIdx.y;
    const int pos = blockIdx.x * 4 + wave;
    if (pos >= MCLS) return;
    const int er = cls >> 1, ec = cls & 1;
    const int mr = pos / 67, mc = pos - mr * 67;

    const int xr = mr - 5 + (lane >> 3), xc = mc - 5 + (lane & 7);
    const float xv = ((unsigned)xr < 64u && (unsigned)xc < 64u) ? img[xr * 64 + xc] : 0.f;

    float xt[4];
    #pragma unroll
    for (int q = 0; q < 4; ++q) {
        const int tt = q * 64 + lane;
        const int a = tt / 15, b = tt - 15 * a;
        const int xi = (((a + er) >> 1) & 7) * 8 + (((b + ec) >> 1) & 7);
        xt[q] = __shfl(xv, xi);
    }

    const float* row = pcvT + ((size_t)(cls * PPAD + pos)) * NTILE2 + lane * 8;
    const float4 v0 = *(const float4*)row;
    const float4 v1 = *(const float4*)(row + 4);
    float vals[8] = {v0.x, v0.y, v0.z, v0.w, v1.x, v1.y, v1.z, v1.w};

    float vmax = vals[0];
    #pragma unroll
    for (int s = 1; s < 8; ++s) vmax = fmaxf(vmax, vals[s]);
    #pragma unroll
    for (int m = 1; m < 64; m <<= 1) vmax = fmaxf(vmax, __shfl_xor(vmax, m));
    const float thr = vmax - MARGIN;

    float best = -3.0e38f; int bn = 0x7FFFFFFF;
    #pragma unroll
    for (int s = 0; s < 8; ++s) {
        unsigned long long bal = __ballot(vals[s] >= thr);
        while (bal) {
            const int src = __ffsll((long long)bal) - 1;
            bal &= bal - 1;
            const float pv = __shfl(vals[s], src);
            const int e = src * 8 + s;                       // entry 0..511
            const int n = ((e >> 1) << 6) | (__float_as_int(pv) & 63);
            const float* mrow = mem + (size_t)n * MDIM;
            float part = 0.f;
            #pragma unroll
            for (int q = 0; q < 4; ++q) {
                const int tt = q * 64 + lane;
                if (tt < MDIM) part = fmaf(mrow[tt], xt[q], part);
            }
            #pragma unroll
            for (int m = 1; m < 64; m <<= 1) part += __shfl_xor(part, m);
            const float sc = part - hn[n];
            if (sc > best || (sc == best && n < bn)) { best = sc; bn = n; }
        }
    }
    if (lane == 0) idx2d[(er + 2 * mr) * L1D + (ec + 2 * mc)] = bn;
}

// ---------------------------------------------------------------------------
// K3: fold, one wave per output pixel.
// ---------------------------------------------------------------------------
__global__ __launch_bounds__(256) void fold_kernel(const float* __restrict__ mem,
                                                   const int* __restrict__ idx2d,
                                                   float* __restrict__ outraw) {
    const int wave = threadIdx.x >> 6, lane = threadIdx.x & 63;
    const int p = blockIdx.x * 4 + wave;   // 0..4095
    const int oi = p >> 6, oj = p & 63;
    float s = 0.f;
    #pragma unroll
    for (int tb = 0; tb < 256; tb += 64) {
        const int tt = tb + lane;
        if (tt < MDIM) {
            const int a = tt / 15, b = tt - 15 * a;
            const int r = 10 + 2 * oi - a, c = 10 + 2 * oj - b;
            if ((unsigned)r < (unsigned)L1D && (unsigned)c < (unsigned)L1D) {
                const int n = idx2d[r * L1D + c];
                s += mem[(size_t)n * MDIM + tt];
            }
        }
    }
    #pragma unroll
    for (int msk = 1; msk < 64; msk <<= 1) s += __shfl_xor(s, msk);
    if (lane == 0) outraw[p] = s;
}

// ---------------------------------------------------------------------------
// K4: divide by global max (single block).
// ---------------------------------------------------------------------------
__global__ __launch_bounds__(256) void norm_kernel(const float* __restrict__ outraw,
                                                   float* __restrict__ out) {
    __shared__ float red[256];
    const int t = threadIdx.x;
    float m = -3.0e38f;
    #pragma unroll
    for (int i = 0; i < 16; ++i) m = fmaxf(m, outraw[t + i * 256]);
    red[t] = m;
    __syncthreads();
    for (int s = 128; s > 0; s >>= 1) {
        if (t < s) red[t] = fmaxf(red[t], red[t + s]);
        __syncthreads();
    }
    const float mx = red[0];
    #pragma unroll
    for (int i = 0; i < 16; ++i) out[t + i * 256] = outraw[t + i * 256] / mx;
}

extern "C" void kernel_launch(void* const* d_in, const int* in_sizes, int n_in,
                              void* d_out, int out_size, void* d_ws, size_t ws_size,
                              hipStream_t stream) {
    const float* img = (const float*)d_in[0];   // 64*64 fp32
    const float* mem = (const float*)d_in[1];   // 16384*225 fp32
    float* out = (float*)d_out;                 // 4096 fp32

    unsigned short* cmh = (unsigned short*)d_ws;              // 4*16384*64 ushort = 8.4 MB
    float* hn = (float*)(cmh + (size_t)4 * NMEM * 64);        // 16384 f
    unsigned int* hnb = (unsigned int*)(hn + NMEM);           // 16384 u32
    unsigned short* xh = (unsigned short*)(hnb + NMEM);       // 294912 ushort
    float* pcvT = (float*)(xh + 294912);                      // 4*4608*512 f = 37.7 MB
    int* idx2d = (int*)(pcvT + (size_t)4 * PPAD * NTILE2);    // 17956 i
    float* outraw = (float*)(idx2d + L1D * L1D);              // 4096 f

    prep_cm<<<(4 * NMEM * 64) / 256, 256, 0, stream>>>(mem, cmh);
    prep_hn<<<NMEM / 4, 256, 0, stream>>>(mem, hn, hnb);
    prep_x<<<144, 256, 0, stream>>>(img, xh);
    mfma_argmin_kernel<<<dim3(256, 4), 256, 0, stream>>>(cmh, xh, hnb, pcvT);
    rescue_kernel<<<dim3((MCLS + 3) / 4, 4), 256, 0, stream>>>(img, mem, hn, pcvT, idx2d);
    fold_kernel<<<1024, 256, 0, stream>>>(mem, idx2d, outraw);
    norm_kernel<<<1, 256, 0, stream>>>(outraw, out);
}

// Round 2
// 163.607 us; speedup vs baseline: 1.0929x; 1.0456x over previous
//
#include <hip/hip_runtime.h>

#define NMEM 16384
#define MDIM 225
#define L1D 134
#define MCLS 4489     // 67*67 real positions per class
#define PPAD 4608     // 144*32 padded positions
#define NTILE2 512    // 256 tiles * 2 surfaced candidates
#define MARGIN 0.5f

typedef __attribute__((ext_vector_type(8))) _Float16 f16x8;
typedef __attribute__((ext_vector_type(16))) float f32x16;

__device__ inline unsigned short f2h(float f) {
    const _Float16 h = (_Float16)f;
    unsigned short u; __builtin_memcpy(&u, &h, 2); return u;
}
__device__ inline _Float16 us2h(unsigned short u) {
    _Float16 h; __builtin_memcpy(&h, &u, 2); return h;
}
__device__ inline float h2f(unsigned short u) { return (float)us2h(u); }

// ---------------------------------------------------------------------------
// P0: collapsed filters -> fp16. One thread per (cls, n, k); cmh[gid].
// prep_hn FUSED in: cls==0 blocks (one wave per n, lanes = k) also compute
// hn[n] = 0.5*||mem_n||^2 (f32) + packed fp16 (-hn_hi,-hn_lo).
// ---------------------------------------------------------------------------
__global__ __launch_bounds__(256) void prep_cm(const float* __restrict__ mem,
                                               unsigned short* __restrict__ cmh,
                                               float* __restrict__ hn,
                                               unsigned int* __restrict__ hnb) {
    const int gid = blockIdx.x * 256 + threadIdx.x;   // 4*16384*64 = 2^22
    const int k = gid & 63, n = (gid >> 6) & (NMEM - 1), cls = gid >> 20;
    const int u = k >> 3, v = k & 7, er = cls >> 1, ec = cls & 1;
    const int i0 = 2 * u - er, j0 = 2 * v - ec;
    const float* mrow = mem + (size_t)n * MDIM;
    float s = 0.f;
    #pragma unroll
    for (int di = 0; di < 2; ++di) {
        const int i = i0 + di;
        if ((unsigned)i >= 15u) continue;
        #pragma unroll
        for (int dj = 0; dj < 2; ++dj) {
            const int j = j0 + dj;
            if ((unsigned)j >= 15u) continue;
            s += mrow[i * 15 + j];
        }
    }
    cmh[gid] = f2h(s);

    if (cls == 0) {   // uniform per block (2^20/256 = 4096 blocks exactly)
        float q = 0.f;
        for (int t = k; t < MDIM; t += 64) { const float v2 = mrow[t]; q += v2 * v2; }
        #pragma unroll
        for (int m = 1; m < 64; m <<= 1) q += __shfl_xor(q, m);
        if (k == 0) {
            const float h = 0.5f * q;
            hn[n] = h;
            const unsigned short nh = f2h(-h);
            const unsigned short nl = f2h(-h - h2f(nh));
            hnb[n] = (unsigned)nh | ((unsigned)nl << 16);
        }
    }
}

// ---------------------------------------------------------------------------
// P2: X (positions) in B-fragment layout, fp16: x[(pt*4+ks)*2+g][lane32][8j].
// ---------------------------------------------------------------------------
__global__ __launch_bounds__(256) void prep_x(const float* __restrict__ img,
                                              unsigned short* __restrict__ xh) {
    const int t = blockIdx.x * 256 + threadIdx.x;   // 144*4*2*32 = 36864
    const int nl = t & 31, g = (t >> 5) & 1, ks = (t >> 6) & 3, pt = t >> 8;
    const int pos = pt * 32 + nl;
    const int u = ks * 2 + g;
    unsigned short h[8];
    if (pos < MCLS) {
        const int mr = pos / 67, mc = pos - mr * 67;
        const int r = mr - 5 + u;
        #pragma unroll
        for (int j = 0; j < 8; ++j) {
            const int c = mc - 5 + j;
            float v = 0.f;
            if ((unsigned)r < 64u && (unsigned)c < 64u) v = img[r * 64 + c];
            h[j] = f2h(v);
        }
    } else {
        #pragma unroll
        for (int j = 0; j < 8; ++j) h[j] = 0;
    }
    #pragma unroll
    for (int j = 0; j < 8; ++j) xh[(size_t)t * 8 + j] = h[j];
}

// ---------------------------------------------------------------------------
// K1: fp16 single-product MFMA scoring. Grid (256 nblk, 4 cls), 4 waves,
// __launch_bounds__(256,4). A (64 n x 64 k) register-resident; -hn folded via
// fp16 hi/lo ext K-slice. B single-buffered (16 regs): next tile prefetched
// into the SAME registers right after the MFMAs consume them; the ~220-cyc
// epilogue hides the L1/L2 latency (xh = 288 KB, L2-hot, read by all blocks).
// No LDS, no barriers.
//
// nblk XCD-write-merge swizzle: (bx&7)*32 + (bx>>3) -> same-XCD blocks own
// consecutive nblk so 8B float2 stores merge into full 64B lines in L2
// (verified R0->R1: WRITE_SIZE 158MB -> 36.9MB).
//
// Epilogue: exact top-2 insert via v_med3_f32: m2=fmed3(m1_old,m2_old,v);
// m1=max(m1_old,v) -- 2 ops/value, no fusion gamble. 6-bit id packed in
// mantissa LSBs via one v_and_or_b32 with a hoisted 16-entry id table
// (idv[r] = (r&3)+8*(r>>2)+4g); acc1 adds "|32" (1 op). Identical top-2 set
// to the pairwise scan -> same surfaced candidates.
// A/B frag: row=lane&31, k=(lane>>5)*8+j. C/D: col=lane&31,
// row=(r&3)+8*(r>>2)+4*(lane>>5)  [HW-verified].
// ---------------------------------------------------------------------------
__global__ __launch_bounds__(256, 4) void mfma_argmin_kernel(const unsigned short* __restrict__ cmh,
                                                             const unsigned short* __restrict__ xh,
                                                             const unsigned int* __restrict__ hnb,
                                                             float* __restrict__ pcvT) {
    const int nblk = ((blockIdx.x & 7) << 5) | (blockIdx.x >> 3);   // XCD write-merge swizzle
    const int cls = blockIdx.y;
    const int t = threadIdx.x, wave = t >> 6, lane = t & 63;
    const int g = lane >> 5, nl = lane & 31;

    // One-time A fragment loads (row nl and nl+32, all 4 K-slices).
    f16x8 a0[4], a1[4];
    #pragma unroll
    for (int ks = 0; ks < 4; ++ks) {
        const size_t base = ((size_t)(cls * NMEM + nblk * 64 + nl)) * 64 + ks * 16 + g * 8;
        a0[ks] = *(const f16x8*)(cmh + base);
        a1[ks] = *(const f16x8*)(cmh + base + 32 * 64);
    }

    // hn-folding ext slice: A_ext=(-hn_hi,-hn_lo,0..), B_ext=(1,1,0..).
    const unsigned int hp0 = hnb[nblk * 64 + nl];
    const unsigned int hp1 = hnb[nblk * 64 + 32 + nl];
    f16x8 aex0 = {0,0,0,0,0,0,0,0}, aex1 = {0,0,0,0,0,0,0,0}, bex = {0,0,0,0,0,0,0,0};
    if (g == 0) {
        aex0[0] = us2h((unsigned short)(hp0 & 0xFFFFu));
        aex0[1] = us2h((unsigned short)(hp0 >> 16));
        aex1[0] = us2h((unsigned short)(hp1 & 0xFFFFu));
        aex1[1] = us2h((unsigned short)(hp1 >> 16));
        bex[0] = (_Float16)1.0f;
        bex[1] = (_Float16)1.0f;
    }

    // Hoisted id table: 16 VGPRs, loop-invariant.
    int idv[16];
    #pragma unroll
    for (int r = 0; r < 16; ++r) idv[r] = (r & 3) + 8 * (r >> 2) + 4 * g;

    // B pointer for this wave/g: pt = it*4+wave  =>  +8192 halves per iter.
    const unsigned short* xp = xh + ((size_t)((wave * 4) * 2 + g)) * 256 + nl * 8;

    // Store pointer: pos = (it*4+wave)*32 + nl advances 128/iter => +65536 f.
    float* stp = pcvT + ((size_t)(cls * PPAD + wave * 32 + nl)) * NTILE2 + nblk * 2;

    f16x8 b[4];
    #pragma unroll
    for (int ks = 0; ks < 4; ++ks) b[ks] = *(const f16x8*)(xp + ks * 512);

    for (int it = 0; it < 36; ++it) {
        f32x16 acc0 = {0.f,0.f,0.f,0.f,0.f,0.f,0.f,0.f,0.f,0.f,0.f,0.f,0.f,0.f,0.f,0.f};
        f32x16 acc1 = {0.f,0.f,0.f,0.f,0.f,0.f,0.f,0.f,0.f,0.f,0.f,0.f,0.f,0.f,0.f,0.f};
        __builtin_amdgcn_s_setprio(1);
        #pragma unroll
        for (int ks = 0; ks < 4; ++ks) {
            acc0 = __builtin_amdgcn_mfma_f32_32x32x16_f16(a0[ks], b[ks], acc0, 0, 0, 0);
            acc1 = __builtin_amdgcn_mfma_f32_32x32x16_f16(a1[ks], b[ks], acc1, 0, 0, 0);
        }
        acc0 = __builtin_amdgcn_mfma_f32_32x32x16_f16(aex0, bex, acc0, 0, 0, 0);
        acc1 = __builtin_amdgcn_mfma_f32_32x32x16_f16(aex1, bex, acc1, 0, 0, 0);
        __builtin_amdgcn_s_setprio(0);

        // Prefetch next B into the SAME registers (WAR-safe: MFMAs above
        // already consumed b). Epilogue below hides the load latency.
        xp += 8192;
        if (it < 35) {
            #pragma unroll
            for (int ks = 0; ks < 4; ++ks) b[ks] = *(const f16x8*)(xp + ks * 512);
        }

        // Exact top-2 insert: m2 = med3(m1_old, m2_old, v); m1 = max(m1_old, v).
        float m1 = -3.0e38f, m2 = -3.0e38f;
        #pragma unroll
        for (int r = 0; r < 16; ++r) {
            const float v = __int_as_float((__float_as_int(acc0[r]) & ~63) | idv[r]);
            m2 = __builtin_amdgcn_fmed3f(m1, m2, v);
            m1 = fmaxf(m1, v);
        }
        #pragma unroll
        for (int r = 0; r < 16; ++r) {
            const float w = __int_as_float(((__float_as_int(acc1[r]) & ~63) | idv[r]) | 32);
            m2 = __builtin_amdgcn_fmed3f(m1, m2, w);
            m1 = fmaxf(m1, w);
        }

        const float o1 = __shfl_xor(m1, 32);
        const float o2 = __shfl_xor(m2, 32);
        const float M1 = fmaxf(m1, o1);
        const float M2 = fmaxf(fminf(m1, o1), fmaxf(m2, o2));

        if (g == 0) {
            float2 st; st.x = M1; st.y = M2;
            *(float2*)stp = st;
        }
        stp += (size_t)128 * NTILE2;
    }
}

// ---------------------------------------------------------------------------
// K2: rescue, one wave per (cls, pos): coalesced read of 512 surfaced
// candidates (256 tiles x top-2), shfl-max vmax, ballot candidates within
// MARGIN, wave-cooperative exact fp32 rescore from mem. Tie rule matches
// argmin-first.
// ---------------------------------------------------------------------------
__global__ __launch_bounds__(256) void rescue_kernel(const float* __restrict__ img,
                                                     const float* __restrict__ mem,
                                                     const float* __restrict__ hn,
                                                     const float* __restrict__ pcvT,
                                                     int* __restrict__ idx2d) {
    const int wave = threadIdx.x >> 6, lane = threadIdx.x & 63;
    const int cls = blockIdx.y;
    const int pos = blockIdx.x * 4 + wave;
    if (pos >= MCLS) return;
    const int er = cls >> 1, ec = cls & 1;
    const int mr = pos / 67, mc = pos - mr * 67;

    const int xr = mr - 5 + (lane >> 3), xc = mc - 5 + (lane & 7);
    const float xv = ((unsigned)xr < 64u && (unsigned)xc < 64u) ? img[xr * 64 + xc] : 0.f;

    float xt[4];
    #pragma unroll
    for (int q = 0; q < 4; ++q) {
        const int tt = q * 64 + lane;
        const int a = tt / 15, b = tt - 15 * a;
        const int xi = (((a + er) >> 1) & 7) * 8 + (((b + ec) >> 1) & 7);
        xt[q] = __shfl(xv, xi);
    }

    const float* row = pcvT + ((size_t)(cls * PPAD + pos)) * NTILE2 + lane * 8;
    const float4 v0 = *(const float4*)row;
    const float4 v1 = *(const float4*)(row + 4);
    float vals[8] = {v0.x, v0.y, v0.z, v0.w, v1.x, v1.y, v1.z, v1.w};

    float vmax = vals[0];
    #pragma unroll
    for (int s = 1; s < 8; ++s) vmax = fmaxf(vmax, vals[s]);
    #pragma unroll
    for (int m = 1; m < 64; m <<= 1) vmax = fmaxf(vmax, __shfl_xor(vmax, m));
    const float thr = vmax - MARGIN;

    float best = -3.0e38f; int bn = 0x7FFFFFFF;
    #pragma unroll
    for (int s = 0; s < 8; ++s) {
        unsigned long long bal = __ballot(vals[s] >= thr);
        while (bal) {
            const int src = __ffsll((long long)bal) - 1;
            bal &= bal - 1;
            const float pv = __shfl(vals[s], src);
            const int e = src * 8 + s;                       // entry 0..511
            const int n = ((e >> 1) << 6) | (__float_as_int(pv) & 63);
            const float* mrow = mem + (size_t)n * MDIM;
            float part = 0.f;
            #pragma unroll
            for (int q = 0; q < 4; ++q) {
                const int tt = q * 64 + lane;
                if (tt < MDIM) part = fmaf(mrow[tt], xt[q], part);
            }
            #pragma unroll
            for (int m = 1; m < 64; m <<= 1) part += __shfl_xor(part, m);
            const float sc = part - hn[n];
            if (sc > best || (sc == best && n < bn)) { best = sc; bn = n; }
        }
    }
    if (lane == 0) idx2d[(er + 2 * mr) * L1D + (ec + 2 * mc)] = bn;
}

// ---------------------------------------------------------------------------
// K3: fold, one wave per output pixel.
// ---------------------------------------------------------------------------
__global__ __launch_bounds__(256) void fold_kernel(const float* __restrict__ mem,
                                                   const int* __restrict__ idx2d,
                                                   float* __restrict__ outraw) {
    const int wave = threadIdx.x >> 6, lane = threadIdx.x & 63;
    const int p = blockIdx.x * 4 + wave;   // 0..4095
    const int oi = p >> 6, oj = p & 63;
    float s = 0.f;
    #pragma unroll
    for (int tb = 0; tb < 256; tb += 64) {
        const int tt = tb + lane;
        if (tt < MDIM) {
            const int a = tt / 15, b = tt - 15 * a;
            const int r = 10 + 2 * oi - a, c = 10 + 2 * oj - b;
            if ((unsigned)r < (unsigned)L1D && (unsigned)c < (unsigned)L1D) {
                const int n = idx2d[r * L1D + c];
                s += mem[(size_t)n * MDIM + tt];
            }
        }
    }
    #pragma unroll
    for (int msk = 1; msk < 64; msk <<= 1) s += __shfl_xor(s, msk);
    if (lane == 0) outraw[p] = s;
}

// ---------------------------------------------------------------------------
// K4: divide by global max (single block).
// ---------------------------------------------------------------------------
__global__ __launch_bounds__(256) void norm_kernel(const float* __restrict__ outraw,
                                                   float* __restrict__ out) {
    __shared__ float red[256];
    const int t = threadIdx.x;
    float m = -3.0e38f;
    #pragma unroll
    for (int i = 0; i < 16; ++i) m = fmaxf(m, outraw[t + i * 256]);
    red[t] = m;
    __syncthreads();
    for (int s = 128; s > 0; s >>= 1) {
        if (t < s) red[t] = fmaxf(red[t], red[t + s]);
        __syncthreads();
    }
    const float mx = red[0];
    #pragma unroll
    for (int i = 0; i < 16; ++i) out[t + i * 256] = outraw[t + i * 256] / mx;
}

extern "C" void kernel_launch(void* const* d_in, const int* in_sizes, int n_in,
                              void* d_out, int out_size, void* d_ws, size_t ws_size,
                              hipStream_t stream) {
    const float* img = (const float*)d_in[0];   // 64*64 fp32
    const float* mem = (const float*)d_in[1];   // 16384*225 fp32
    float* out = (float*)d_out;                 // 4096 fp32

    unsigned short* cmh = (unsigned short*)d_ws;              // 4*16384*64 ushort = 8.4 MB
    float* hn = (float*)(cmh + (size_t)4 * NMEM * 64);        // 16384 f
    unsigned int* hnb = (unsigned int*)(hn + NMEM);           // 16384 u32
    unsigned short* xh = (unsigned short*)(hnb + NMEM);       // 294912 ushort
    float* pcvT = (float*)(xh + 294912);                      // 4*4608*512 f = 37.7 MB
    int* idx2d = (int*)(pcvT + (size_t)4 * PPAD * NTILE2);    // 17956 i
    float* outraw = (float*)(idx2d + L1D * L1D);              // 4096 f

    prep_cm<<<(4 * NMEM * 64) / 256, 256, 0, stream>>>(mem, cmh, hn, hnb);
    prep_x<<<144, 256, 0, stream>>>(img, xh);
    mfma_argmin_kernel<<<dim3(256, 4), 256, 0, stream>>>(cmh, xh, hnb, pcvT);
    rescue_kernel<<<dim3((MCLS + 3) / 4, 4), 256, 0, stream>>>(img, mem, hn, pcvT, idx2d);
    fold_kernel<<<1024, 256, 0, stream>>>(mem, idx2d, outraw);
    norm_kernel<<<1, 256, 0, stream>>>(outraw, out);
}